// Round 3
// baseline (442.848 us; speedup 1.0000x reference)
//
#include <hip/hip_runtime.h>

typedef __attribute__((ext_vector_type(8))) short short8;
typedef __attribute__((ext_vector_type(4))) float f32x4;
typedef unsigned short u16;
typedef unsigned int u32;

#define S_ 8192
#define DM_ 1024
#define DK_ 512
#define SCALE_INV 0.044194173824159216f  // 1/sqrt(512)

__device__ __forceinline__ float bf2f(u16 h){
  u32 u = ((u32)h) << 16;
  float f;
  __builtin_memcpy(&f, &u, 4);
  return f;
}
__device__ __forceinline__ u16 f2bf(float f){
  u32 u;
  __builtin_memcpy(&u, &f, 4);
  return (u16)((u + 0x7FFFu + ((u >> 16) & 1u)) >> 16);
}

// flat lower-tri index -> (row-block, col-block), t = rb*(rb+1)/2 + jt
__device__ __forceinline__ void tri_decode(int t, int& rb, int& jt){
  float f = sqrtf(8.0f * (float)t + 1.0f);
  int r = (int)((f - 1.0f) * 0.5f);
  while ((r + 1) * (r + 2) / 2 <= t) ++r;
  while (r * (r + 1) / 2 > t) --r;
  rb = r; jt = t - r * (r + 1) / 2;
}

// ---- global -> LDS staging of a 256x64 bf16 tile, 1024 threads, 16B/lane DMA.
// 16B chunks XOR-swizzled within each 128B row so ds_read_b128 fragment reads
// (row varies with lane&15) land on distinct bank groups.
__device__ __forceinline__ void stage256x64(const u16* g, int ld, u16* lds, int tid){
  int w = tid >> 6, l = tid & 63;
#pragma unroll
  for (int p = 0; p < 2; ++p){
    int s = ((w << 1) + p) * 64 + l;    // 16B-slot index 0..2047
    int r = s >> 3;                      // row 0..255
    int bp = s & 7;                      // swizzled chunk position in row
    int b = bp ^ (r & 7);                // source chunk in global row
    const u16* src = g + (size_t)r * ld + (b << 3);
    __builtin_amdgcn_global_load_lds(
        (const __attribute__((address_space(1))) void*)src,
        (__attribute__((address_space(3))) void*)(lds + (((w << 1) + p) << 9)),
        16, 0, 0);
  }
}

__device__ __forceinline__ short8 ldsFrag(const u16* lds, int row, int kc){
  return *(const short8*)(lds + row * 64 + ((kc ^ (row & 7)) << 3));
}

// one BK=64 stage for a 64x64 wave tile: 32 MFMAs
__device__ __forceinline__ void mfma_step(const u16* ldsA, const u16* ldsB,
                                          f32x4 acc[4][4], int wrow, int wcol,
                                          int quad, int l15){
#pragma unroll
  for (int half = 0; half < 2; ++half){
    int kc = (half << 2) + quad;
    short8 av[4], bv[4];
#pragma unroll
    for (int mi = 0; mi < 4; ++mi) av[mi] = ldsFrag(ldsA, wrow + mi * 16 + l15, kc);
#pragma unroll
    for (int ni = 0; ni < 4; ++ni) bv[ni] = ldsFrag(ldsB, wcol + ni * 16 + l15, kc);
#pragma unroll
    for (int mi = 0; mi < 4; ++mi)
#pragma unroll
      for (int ni = 0; ni < 4; ++ni)
        acc[mi][ni] = __builtin_amdgcn_mfma_f32_16x16x32_bf16(av[mi], bv[ni], acc[mi][ni], 0, 0, 0);
  }
}

// C[256x256] += A[256 x 64*nK] * B^T  (1024 threads, 4x4 wave grid of 64x64)
__device__ __forceinline__ void gemm_tile256(const u16* A, int lda, const u16* B, int ldb,
                                             int nK, u16* ldsA, u16* ldsB,
                                             f32x4 acc[4][4], int tid){
  int lane = tid & 63, w = tid >> 6;
  int wrow = (w >> 2) << 6, wcol = (w & 3) << 6;
  int quad = lane >> 4, l15 = lane & 15;
  for (int ks = 0; ks < nK; ++ks){
    stage256x64(A + ks * 64, lda, ldsA, tid);
    stage256x64(B + ks * 64, ldb, ldsB, tid);
    __syncthreads();
    mfma_step(ldsA, ldsB, acc, wrow, wcol, quad, l15);
    __syncthreads();
  }
}

// ---------------- kernels ----------------

__global__ void sha_cvt(const float* __restrict__ src, u16* __restrict__ dst, int n4){
  int i = blockIdx.x * blockDim.x + threadIdx.x;
  if (i >= n4) return;
  float4 v = ((const float4*)src)[i];
  ushort4 h;
  h.x = f2bf(v.x); h.y = f2bf(v.y); h.z = f2bf(v.z); h.w = f2bf(v.w);
  ((ushort4*)dst)[i] = h;
}

__global__ void sha_csinit(float* colsum){
  int j = blockIdx.x * 256 + threadIdx.x;
  colsum[j] = (float)j;   // j masked entries each contribute exp(0)=1
}

// fused Q/K/V projection: O = X @ W.T + b, bf16 out. 256x256 tiles.
__global__ __launch_bounds__(1024) void sha_proj(
    const u16* Xq, const u16* Xk, const u16* Xv,
    const u16* Wq, const u16* Wk, const u16* Wv,
    const float* bq, const float* bk, const float* bv,
    u16* Oq, u16* Ok, u16* Ov){
  __shared__ u16 ldsA[256 * 64], ldsB[256 * 64];
  int z = blockIdx.z;
  const u16* X = (z == 0) ? Xq : (z == 1) ? Xk : Xv;
  const u16* W = (z == 0) ? Wq : (z == 1) ? Wk : Wv;
  const float* bias = (z == 0) ? bq : (z == 1) ? bk : bv;
  u16* O = (z == 0) ? Oq : (z == 1) ? Ok : Ov;
  int tid = threadIdx.x;
  int i0 = blockIdx.y << 8, n0 = blockIdx.x << 8;
  f32x4 zero4 = {0.f, 0.f, 0.f, 0.f};
  f32x4 acc[4][4];
#pragma unroll
  for (int mi = 0; mi < 4; ++mi)
#pragma unroll
    for (int ni = 0; ni < 4; ++ni) acc[mi][ni] = zero4;
  gemm_tile256(X + (size_t)i0 * DM_, DM_, W + (size_t)n0 * DM_, DM_, 16, ldsA, ldsB, acc, tid);
  int lane = tid & 63, w = tid >> 6;
  int wrow = (w >> 2) << 6, wcol = (w & 3) << 6, quad = lane >> 4, l15 = lane & 15;
#pragma unroll
  for (int ni = 0; ni < 4; ++ni){
    int n = wcol + ni * 16 + l15;
    float bn = bias[n0 + n];
#pragma unroll
    for (int mi = 0; mi < 4; ++mi)
#pragma unroll
      for (int r = 0; r < 4; ++r){
        int m = wrow + mi * 16 + quad * 4 + r;
        O[(size_t)(i0 + m) * DK_ + n0 + n] = f2bf(acc[mi][ni][r] + bn);
      }
  }
}

// lower-triangle: P = exp(qp @ kp^T / sqrt(dk)) (masked), store bf16 packed-tri
// (256x256 tiles on a 32x32 tri grid), accumulate column sums.
__global__ __launch_bounds__(1024) void sha_pexp(const u16* qp, const u16* kp,
                                                 u16* P, float* colsum){
  int rb, jt;
  tri_decode(blockIdx.x, rb, jt);
  __shared__ u16 ldsA[256 * 64], ldsB[256 * 64];
  __shared__ float cs[256];
  int tid = threadIdx.x;
  int lane = tid & 63, w = tid >> 6;
  int wrow = (w >> 2) << 6, wcol = (w & 3) << 6, quad = lane >> 4, l15 = lane & 15;
  int i0 = rb << 8, j0 = jt << 8;
  f32x4 zero4 = {0.f, 0.f, 0.f, 0.f};
  f32x4 acc[4][4];
#pragma unroll
  for (int mi = 0; mi < 4; ++mi)
#pragma unroll
    for (int ni = 0; ni < 4; ++ni) acc[mi][ni] = zero4;
  if (tid < 256) cs[tid] = 0.f;
  gemm_tile256(qp + (size_t)i0 * DK_, DK_, kp + (size_t)j0 * DK_, DK_, 8, ldsA, ldsB, acc, tid);
  u16* Pt = P + (size_t)blockIdx.x * (256 * 256);
  float psum[4] = {0.f, 0.f, 0.f, 0.f};
#pragma unroll
  for (int mi = 0; mi < 4; ++mi){
#pragma unroll
    for (int ni = 0; ni < 4; ++ni){
      int n = wcol + ni * 16 + l15;
#pragma unroll
      for (int r = 0; r < 4; ++r){
        int m = wrow + mi * 16 + quad * 4 + r;
        float e = 0.f;
        if (i0 + m >= j0 + n) e = __expf(acc[mi][ni][r] * SCALE_INV);
        Pt[m * 256 + n] = f2bf(e);
        psum[ni] += e;
      }
    }
  }
#pragma unroll
  for (int ni = 0; ni < 4; ++ni){
    float vsum = psum[ni];
    vsum += __shfl_xor(vsum, 16);
    vsum += __shfl_xor(vsum, 32);
    if (quad == 0) atomicAdd(&cs[wcol + ni * 16 + l15], vsum);
  }
  __syncthreads();
  if (tid < 256) unsafeAtomicAdd(&colsum[j0 + tid], cs[tid]);
}

// vpp = vp / colsum (row-wise), also write transposed copy for PV B-operand
__global__ __launch_bounds__(256) void sha_scaleT(const u16* vp, const float* colsum,
                                                  u16* vpp, u16* vppT){
  __shared__ float inv[128];
  __shared__ u16 t[128 * 130];
  int db = blockIdx.x, jb = blockIdx.y;
  int j0 = jb << 7, d0 = db << 7;
  int tid = threadIdx.x;
  if (tid < 128) inv[tid] = 1.0f / colsum[j0 + tid];
  __syncthreads();
#pragma unroll
  for (int rep = 0; rep < 64; ++rep){
    int idx = rep * 256 + tid;
    int r = idx >> 7, c = idx & 127;
    float val = bf2f(vp[(size_t)(j0 + r) * DK_ + d0 + c]) * inv[r];
    u16 h = f2bf(val);
    vpp[(size_t)(j0 + r) * DK_ + d0 + c] = h;
    t[c * 130 + r] = h;
  }
  __syncthreads();
#pragma unroll
  for (int rep = 0; rep < 64; ++rep){
    int idx = rep * 256 + tid;
    int rT = idx & 127, cT = idx >> 7;
    vppT[(size_t)(d0 + cT) * S_ + j0 + rT] = t[cT * 130 + rT];
  }
}

// suffix-sum pass A: per-chunk (256 rows) column partial sums
__global__ __launch_bounds__(256) void sha_suma(const u16* vpp, float* part){
  __shared__ float red[256];
  int db = blockIdx.x, c = blockIdx.y;
  int tid = threadIdx.x;
  int d = (db << 7) + (tid & 127);
  int half = tid >> 7;
  float s = 0.f;
  int r0 = c * 256 + half * 128;
  for (int r = 0; r < 128; ++r)
    s += bf2f(vpp[(size_t)(r0 + r) * DK_ + d]);
  red[tid] = s;
  __syncthreads();
  if (tid < 128) part[c * DK_ + (db << 7) + tid] = red[tid] + red[tid + 128];
}

// suffix-sum pass B: out[i,d] = sum_{j>i} vpp[j,d]  (initializes out)
__global__ __launch_bounds__(128) void sha_sumb(const u16* vpp, const float* part, float* out){
  int db = blockIdx.x, c = blockIdx.y;
  int tid = threadIdx.x;
  int d = (db << 7) + tid;
  float run = 0.f;
  for (int cc = c + 1; cc < 32; ++cc) run += part[cc * DK_ + d];
  for (int r = 255; r >= 0; --r){
    int i = c * 256 + r;
    out[(size_t)i * DK_ + d] = run;
    run += bf2f(vpp[(size_t)i * DK_ + d]);
  }
}

// out += P(tri,256-tiles) @ vpp. Block: 256 rows x 256 d, chunk of 2 j-tiles.
// rb descending so long blocks dispatch first.
__global__ __launch_bounds__(1024) void sha_pv(const u16* P, const u16* vppT, float* out){
  int db = blockIdx.x;
  int rb = 31 - blockIdx.y;
  int jc = blockIdx.z;
  if (jc * 2 > rb) return;
  __shared__ u16 ldsA[256 * 64], ldsB[256 * 64];
  int tid = threadIdx.x;
  int i0 = rb << 8, d0 = db << 8;
  f32x4 zero4 = {0.f, 0.f, 0.f, 0.f};
  f32x4 acc[4][4];
#pragma unroll
  for (int mi = 0; mi < 4; ++mi)
#pragma unroll
    for (int ni = 0; ni < 4; ++ni) acc[mi][ni] = zero4;
  int jtEnd = min(jc * 2 + 2, rb + 1);
  for (int jt = jc * 2; jt < jtEnd; ++jt){
    const u16* Pt = P + (size_t)(rb * (rb + 1) / 2 + jt) * (256 * 256);
    gemm_tile256(Pt, 256, vppT + (size_t)d0 * S_ + (jt << 8), S_, 4, ldsA, ldsB, acc, tid);
  }
  int lane = tid & 63, w = tid >> 6;
  int wrow = (w >> 2) << 6, wcol = (w & 3) << 6, quad = lane >> 4, l15 = lane & 15;
#pragma unroll
  for (int mi = 0; mi < 4; ++mi)
#pragma unroll
    for (int ni = 0; ni < 4; ++ni)
#pragma unroll
      for (int r = 0; r < 4; ++r){
        int m = wrow + mi * 16 + quad * 4 + r;
        int n = wcol + ni * 16 + l15;
        unsafeAtomicAdd(&out[(size_t)(i0 + m) * DK_ + d0 + n], acc[mi][ni][r]);
      }
}

extern "C" void kernel_launch(void* const* d_in, const int* in_sizes, int n_in,
                              void* d_out, int out_size, void* d_ws, size_t ws_size,
                              hipStream_t stream){
  const float* q   = (const float*)d_in[0];
  const float* k   = (const float*)d_in[1];
  const float* v   = (const float*)d_in[2];
  const float* WQw = (const float*)d_in[3];
  const float* WQb = (const float*)d_in[4];
  const float* WKw = (const float*)d_in[5];
  const float* WKb = (const float*)d_in[6];
  const float* WVw = (const float*)d_in[7];
  const float* WVb = (const float*)d_in[8];
  float* out = (float*)d_out;
  (void)in_sizes; (void)n_in; (void)out_size;

  char* ws = (char*)d_ws;
  size_t off = 0;
  auto alloc = [&](size_t bytes){ void* p = ws + off; off += (bytes + 255) & ~(size_t)255; return p; };
  u16* qbf  = (u16*)alloc((size_t)S_ * DM_ * 2);
  u16* kbf  = (u16*)alloc((size_t)S_ * DM_ * 2);
  u16* vbf  = (u16*)alloc((size_t)S_ * DM_ * 2);
  u16* wqb  = (u16*)alloc((size_t)DK_ * DM_ * 2);
  u16* wkb  = (u16*)alloc((size_t)DK_ * DM_ * 2);
  u16* wvb  = (u16*)alloc((size_t)DK_ * DM_ * 2);
  u16* qp   = (u16*)alloc((size_t)S_ * DK_ * 2);
  u16* kp   = (u16*)alloc((size_t)S_ * DK_ * 2);
  u16* vp   = (u16*)alloc((size_t)S_ * DK_ * 2);
  u16* vpp  = (u16*)alloc((size_t)S_ * DK_ * 2);
  u16* vppT = (u16*)alloc((size_t)S_ * DK_ * 2);
  float* colsum = (float*)alloc((size_t)S_ * 4);
  float* part   = (float*)alloc((size_t)32 * DK_ * 4);
  u16* P    = (u16*)alloc((size_t)528 * 256 * 256 * 2);
  if (ws_size < off) return;  // insufficient workspace -> visible as validation failure

  sha_cvt<<<dim3(S_ * DM_ / 4 / 256), 256, 0, stream>>>(q, qbf, S_ * DM_ / 4);
  sha_cvt<<<dim3(S_ * DM_ / 4 / 256), 256, 0, stream>>>(k, kbf, S_ * DM_ / 4);
  sha_cvt<<<dim3(S_ * DM_ / 4 / 256), 256, 0, stream>>>(v, vbf, S_ * DM_ / 4);
  sha_cvt<<<dim3(DK_ * DM_ / 4 / 256), 256, 0, stream>>>(WQw, wqb, DK_ * DM_ / 4);
  sha_cvt<<<dim3(DK_ * DM_ / 4 / 256), 256, 0, stream>>>(WKw, wkb, DK_ * DM_ / 4);
  sha_cvt<<<dim3(DK_ * DM_ / 4 / 256), 256, 0, stream>>>(WVw, wvb, DK_ * DM_ / 4);
  sha_csinit<<<dim3(S_ / 256), 256, 0, stream>>>(colsum);
  sha_proj<<<dim3(2, 32, 3), 1024, 0, stream>>>(qbf, kbf, vbf, wqb, wkb, wvb,
                                                WQb, WKb, WVb, qp, kp, vp);
  sha_pexp<<<dim3(528), 1024, 0, stream>>>(qp, kp, P, colsum);
  sha_scaleT<<<dim3(4, 64), 256, 0, stream>>>(vp, colsum, vpp, vppT);
  sha_suma<<<dim3(4, 32), 256, 0, stream>>>(vpp, part);
  sha_sumb<<<dim3(4, 32), 128, 0, stream>>>(vpp, part, out);
  sha_pv<<<dim3(2, 32, 16), 1024, 0, stream>>>(P, vppT, out);
}

// Round 4
// 389.135 us; speedup vs baseline: 1.1380x; 1.1380x over previous
//
#include <hip/hip_runtime.h>

typedef __attribute__((ext_vector_type(8))) short short8;
typedef __attribute__((ext_vector_type(4))) float f32x4;
typedef unsigned short u16;
typedef unsigned int u32;

#define S_ 8192
#define DM_ 1024
#define DK_ 512
#define SCALE_INV 0.044194173824159216f  // 1/sqrt(512)

__device__ __forceinline__ float bf2f(u16 h){
  u32 u = ((u32)h) << 16;
  float f;
  __builtin_memcpy(&f, &u, 4);
  return f;
}
__device__ __forceinline__ u16 f2bf(float f){
  u32 u;
  __builtin_memcpy(&u, &f, 4);
  return (u16)((u + 0x7FFFu + ((u >> 16) & 1u)) >> 16);
}

// flat lower-tri index -> (row-block, col-block), t = rb*(rb+1)/2 + jt
__device__ __forceinline__ void tri_decode(int t, int& rb, int& jt){
  float f = sqrtf(8.0f * (float)t + 1.0f);
  int r = (int)((f - 1.0f) * 0.5f);
  while ((r + 1) * (r + 2) / 2 <= t) ++r;
  while (r * (r + 1) / 2 > t) --r;
  rb = r; jt = t - r * (r + 1) / 2;
}

// ---- global -> LDS staging of a 128x64 bf16 tile, 256 threads, 16B/lane DMA.
// 16B chunks XOR-swizzled within each 128B row so ds_read_b128 fragment
// reads (row varies with lane&15) land on distinct bank groups.
__device__ __forceinline__ void stage128x64(const u16* g, int ld, u16* lds, int tid){
  int w = tid >> 6, l = tid & 63;
#pragma unroll
  for (int is = 0; is < 4; ++is){
    int s = ((w << 2) + is) * 64 + l;   // 16B-slot index 0..511
    int r = s >> 3;                      // row 0..127
    int bp = s & 7;                      // swizzled chunk position in row
    int b = bp ^ (r & 7);                // source chunk in global row
    const u16* src = g + (size_t)r * ld + (b << 3);
    __builtin_amdgcn_global_load_lds(
        (const __attribute__((address_space(1))) void*)src,
        (__attribute__((address_space(3))) void*)(lds + (((w << 2) + is) << 9)),
        16, 0, 0);
  }
}

__device__ __forceinline__ short8 ldsFrag(const u16* lds, int row, int kc){
  return *(const short8*)(lds + row * 64 + ((kc ^ (row & 7)) << 3));
}

// one BK=64 stage for a 64x64 wave tile: 16 ds_read_b128 + 32 MFMAs
__device__ __forceinline__ void mfma_step(const u16* ldsA, const u16* ldsB,
                                          f32x4 acc[4][4], int wrow, int wcol,
                                          int quad, int l15){
#pragma unroll
  for (int half = 0; half < 2; ++half){
    int kc = (half << 2) + quad;
    short8 av[4], bv[4];
#pragma unroll
    for (int mi = 0; mi < 4; ++mi) av[mi] = ldsFrag(ldsA, wrow + mi * 16 + l15, kc);
#pragma unroll
    for (int ni = 0; ni < 4; ++ni) bv[ni] = ldsFrag(ldsB, wcol + ni * 16 + l15, kc);
#pragma unroll
    for (int mi = 0; mi < 4; ++mi)
#pragma unroll
      for (int ni = 0; ni < 4; ++ni)
        acc[mi][ni] = __builtin_amdgcn_mfma_f32_16x16x32_bf16(av[mi], bv[ni], acc[mi][ni], 0, 0, 0);
  }
}

// C[128x128] += A[128 x 64*nK] * B^T  (256 threads, 2x2 wave grid of 64x64)
__device__ __forceinline__ void gemm_tile(const u16* A, int lda, const u16* B, int ldb,
                                          int nK, u16* ldsA, u16* ldsB,
                                          f32x4 acc[4][4], int tid){
  int lane = tid & 63, w = tid >> 6;
  int wrow = (w >> 1) << 6, wcol = (w & 1) << 6;
  int quad = lane >> 4, l15 = lane & 15;
  for (int ks = 0; ks < nK; ++ks){
    stage128x64(A + ks * 64, lda, ldsA, tid);
    stage128x64(B + ks * 64, ldb, ldsB, tid);
    __syncthreads();
    mfma_step(ldsA, ldsB, acc, wrow, wcol, quad, l15);
    __syncthreads();
  }
}

// ---------------- kernels ----------------

// one launch: all six fp32->bf16 conversions + colsum init
__global__ __launch_bounds__(256) void sha_cvt_all(
    const float* q, const float* k, const float* v,
    const float* wq, const float* wk, const float* wv,
    u16* qb, u16* kb, u16* vb, u16* wqb, u16* wkb, u16* wvb,
    float* colsum){
  const int NQ = S_ * DM_ / 4, NW = DK_ * DM_ / 4;
  int t = blockIdx.x * 256 + threadIdx.x;
  if (t < 3 * NQ){
    const float* s = t < NQ ? q : (t < 2 * NQ ? k : v);
    u16* d = t < NQ ? qb : (t < 2 * NQ ? kb : vb);
    int i = t < NQ ? t : (t < 2 * NQ ? t - NQ : t - 2 * NQ);
    float4 x = ((const float4*)s)[i];
    ushort4 h; h.x = f2bf(x.x); h.y = f2bf(x.y); h.z = f2bf(x.z); h.w = f2bf(x.w);
    ((ushort4*)d)[i] = h;
  } else {
    int u = t - 3 * NQ;
    if (u < 3 * NW){
      const float* s = u < NW ? wq : (u < 2 * NW ? wk : wv);
      u16* d = u < NW ? wqb : (u < 2 * NW ? wkb : wvb);
      int i = u < NW ? u : (u < 2 * NW ? u - NW : u - 2 * NW);
      float4 x = ((const float4*)s)[i];
      ushort4 h; h.x = f2bf(x.x); h.y = f2bf(x.y); h.z = f2bf(x.z); h.w = f2bf(x.w);
      ((ushort4*)d)[i] = h;
    } else {
      int j = u - 3 * NW;
      if (j < S_) colsum[j] = (float)j;  // j masked entries contribute exp(0)=1
    }
  }
}

// fused Q/K/V projection: O = X @ W.T + b, bf16 out. 128x128 tiles.
__global__ __launch_bounds__(256) void sha_proj(
    const u16* Xq, const u16* Xk, const u16* Xv,
    const u16* Wq, const u16* Wk, const u16* Wv,
    const float* bq, const float* bk, const float* bv,
    u16* Oq, u16* Ok, u16* Ov){
  __shared__ u16 ldsA[128 * 64], ldsB[128 * 64];
  int z = blockIdx.z;
  const u16* X = (z == 0) ? Xq : (z == 1) ? Xk : Xv;
  const u16* W = (z == 0) ? Wq : (z == 1) ? Wk : Wv;
  const float* bias = (z == 0) ? bq : (z == 1) ? bk : bv;
  u16* O = (z == 0) ? Oq : (z == 1) ? Ok : Ov;
  int tid = threadIdx.x;
  int i0 = blockIdx.y << 7, n0 = blockIdx.x << 7;
  f32x4 zero4 = {0.f, 0.f, 0.f, 0.f};
  f32x4 acc[4][4];
#pragma unroll
  for (int mi = 0; mi < 4; ++mi)
#pragma unroll
    for (int ni = 0; ni < 4; ++ni) acc[mi][ni] = zero4;
  gemm_tile(X + (size_t)i0 * DM_, DM_, W + (size_t)n0 * DM_, DM_, 16, ldsA, ldsB, acc, tid);
  int lane = tid & 63, w = tid >> 6;
  int wrow = (w >> 1) << 6, wcol = (w & 1) << 6, quad = lane >> 4, l15 = lane & 15;
#pragma unroll
  for (int ni = 0; ni < 4; ++ni){
    int n = wcol + ni * 16 + l15;
    float bn = bias[n0 + n];
#pragma unroll
    for (int mi = 0; mi < 4; ++mi)
#pragma unroll
      for (int r = 0; r < 4; ++r){
        int m = wrow + mi * 16 + quad * 4 + r;
        O[(size_t)(i0 + m) * DK_ + n0 + n] = f2bf(acc[mi][ni][r] + bn);
      }
  }
}

// lower-triangle: P = exp(qp @ kp^T / sqrt(dk)) (masked), store bf16 packed-tri,
// accumulate column sums. One block per 128x128 tile: 2080 uniform blocks.
__global__ __launch_bounds__(256) void sha_pexp(const u16* qp, const u16* kp,
                                                u16* P, float* colsum){
  int rb, jt;
  tri_decode(blockIdx.x, rb, jt);
  __shared__ u16 ldsA[128 * 64], ldsB[128 * 64];
  __shared__ float cs[128];
  int tid = threadIdx.x;
  int lane = tid & 63, w = tid >> 6;
  int wrow = (w >> 1) << 6, wcol = (w & 1) << 6, quad = lane >> 4, l15 = lane & 15;
  int i0 = rb << 7, j0 = jt << 7;
  f32x4 zero4 = {0.f, 0.f, 0.f, 0.f};
  f32x4 acc[4][4];
#pragma unroll
  for (int mi = 0; mi < 4; ++mi)
#pragma unroll
    for (int ni = 0; ni < 4; ++ni) acc[mi][ni] = zero4;
  if (tid < 128) cs[tid] = 0.f;
  gemm_tile(qp + (size_t)i0 * DK_, DK_, kp + (size_t)j0 * DK_, DK_, 8, ldsA, ldsB, acc, tid);
  u16* Pt = P + (size_t)blockIdx.x * (128 * 128);
  float psum[4] = {0.f, 0.f, 0.f, 0.f};
  int diag = (jt == rb);
#pragma unroll
  for (int mi = 0; mi < 4; ++mi){
#pragma unroll
    for (int ni = 0; ni < 4; ++ni){
      int n = wcol + ni * 16 + l15;
#pragma unroll
      for (int r = 0; r < 4; ++r){
        int m = wrow + mi * 16 + quad * 4 + r;
        float e = 0.f;
        if (!diag || m >= n) e = __expf(acc[mi][ni][r] * SCALE_INV);
        Pt[m * 128 + n] = f2bf(e);
        psum[ni] += e;
      }
    }
  }
#pragma unroll
  for (int ni = 0; ni < 4; ++ni){
    float vsum = psum[ni];
    vsum += __shfl_xor(vsum, 16);
    vsum += __shfl_xor(vsum, 32);
    if (quad == 0) atomicAdd(&cs[wcol + ni * 16 + l15], vsum);
  }
  __syncthreads();
  if (tid < 128) unsafeAtomicAdd(&colsum[j0 + tid], cs[tid]);
}

// vpp = vp / colsum (row-wise), transposed copy for PV B-operand, and
// per-64-row column partial sums (fused former suma).
__global__ __launch_bounds__(256) void sha_scaleT(const u16* vp, const float* colsum,
                                                  u16* vpp, u16* vppT, float* part){
  __shared__ float inv[128];
  __shared__ u16 t[128 * 130];
  __shared__ float red[2][256];
  int db = blockIdx.x, jb = blockIdx.y;
  int j0 = jb << 7, d0 = db << 7;
  int tid = threadIdx.x;
  if (tid < 128) inv[tid] = 1.0f / colsum[j0 + tid];
  __syncthreads();
  int p = tid >> 7, c = tid & 127;
  float s0 = 0.f, s1 = 0.f;
#pragma unroll
  for (int rep = 0; rep < 64; ++rep){
    int r = rep * 2 + p;               // this thread's rows have fixed column c
    float val = bf2f(vp[(size_t)(j0 + r) * DK_ + d0 + c]) * inv[r];
    u16 h = f2bf(val);
    vpp[(size_t)(j0 + r) * DK_ + d0 + c] = h;
    t[c * 130 + r] = h;
    if (r < 64) s0 += val; else s1 += val;
  }
  red[0][tid] = s0; red[1][tid] = s1;
  __syncthreads();
#pragma unroll
  for (int rep = 0; rep < 64; ++rep){
    int idx = rep * 256 + tid;
    int rT = idx & 127, cT = idx >> 7;
    vppT[(size_t)(d0 + cT) * S_ + j0 + rT] = t[cT * 130 + rT];
  }
  if (tid < 128){
    part[(size_t)(jb * 2 + 0) * DK_ + d0 + tid] = red[0][tid] + red[0][tid + 128];
    part[(size_t)(jb * 2 + 1) * DK_ + d0 + tid] = red[1][tid] + red[1][tid + 128];
  }
}

// suffix pass: out[i,d] = sum_{j>i} vpp[j,d], 64-row chunks (128 chunks, 512 blocks)
__global__ __launch_bounds__(128) void sha_sumb(const u16* vpp, const float* part, float* out){
  int db = blockIdx.x, c = blockIdx.y;
  int tid = threadIdx.x;
  int d = (db << 7) + tid;
  float run = 0.f;
  for (int cc = c + 1; cc < 128; ++cc) run += part[(size_t)cc * DK_ + d];
  for (int r = 63; r >= 0; --r){
    int i = (c << 6) + r;
    out[(size_t)i * DK_ + d] = run;
    run += bf2f(vpp[(size_t)i * DK_ + d]);
  }
}

// out += P(tri) @ vpp. Chunk of 8 j-tiles (halved atomic volume), rb descending.
__global__ __launch_bounds__(256) void sha_pv(const u16* P, const u16* vppT, float* out){
  int db = blockIdx.x;
  int rb = 63 - blockIdx.y;
  int jc = blockIdx.z;
  if (jc * 8 > rb) return;
  __shared__ u16 ldsA[128 * 64], ldsB[128 * 64];
  int tid = threadIdx.x;
  int i0 = rb << 7, d0 = db << 7;
  f32x4 zero4 = {0.f, 0.f, 0.f, 0.f};
  f32x4 acc[4][4];
#pragma unroll
  for (int mi = 0; mi < 4; ++mi)
#pragma unroll
    for (int ni = 0; ni < 4; ++ni) acc[mi][ni] = zero4;
  int jtEnd = min(jc * 8 + 8, rb + 1);
  for (int jt = jc * 8; jt < jtEnd; ++jt){
    const u16* Pt = P + (size_t)(rb * (rb + 1) / 2 + jt) * (128 * 128);
    gemm_tile(Pt, 128, vppT + (size_t)d0 * S_ + (jt << 7), S_, 2, ldsA, ldsB, acc, tid);
  }
  int lane = tid & 63, w = tid >> 6;
  int wrow = (w >> 1) << 6, wcol = (w & 1) << 6, quad = lane >> 4, l15 = lane & 15;
#pragma unroll
  for (int mi = 0; mi < 4; ++mi)
#pragma unroll
    for (int ni = 0; ni < 4; ++ni)
#pragma unroll
      for (int r = 0; r < 4; ++r){
        int m = wrow + mi * 16 + quad * 4 + r;
        int n = wcol + ni * 16 + l15;
        unsafeAtomicAdd(&out[(size_t)(i0 + m) * DK_ + d0 + n], acc[mi][ni][r]);
      }
}

extern "C" void kernel_launch(void* const* d_in, const int* in_sizes, int n_in,
                              void* d_out, int out_size, void* d_ws, size_t ws_size,
                              hipStream_t stream){
  const float* q   = (const float*)d_in[0];
  const float* k   = (const float*)d_in[1];
  const float* v   = (const float*)d_in[2];
  const float* WQw = (const float*)d_in[3];
  const float* WQb = (const float*)d_in[4];
  const float* WKw = (const float*)d_in[5];
  const float* WKb = (const float*)d_in[6];
  const float* WVw = (const float*)d_in[7];
  const float* WVb = (const float*)d_in[8];
  float* out = (float*)d_out;
  (void)in_sizes; (void)n_in; (void)out_size;

  char* ws = (char*)d_ws;
  size_t off = 0;
  auto alloc = [&](size_t bytes){ void* p = ws + off; off += (bytes + 255) & ~(size_t)255; return p; };
  u16* qbf  = (u16*)alloc((size_t)S_ * DM_ * 2);
  u16* kbf  = (u16*)alloc((size_t)S_ * DM_ * 2);
  u16* vbf  = (u16*)alloc((size_t)S_ * DM_ * 2);
  u16* wqb  = (u16*)alloc((size_t)DK_ * DM_ * 2);
  u16* wkb  = (u16*)alloc((size_t)DK_ * DM_ * 2);
  u16* wvb  = (u16*)alloc((size_t)DK_ * DM_ * 2);
  u16* qp   = (u16*)alloc((size_t)S_ * DK_ * 2);
  u16* kp   = (u16*)alloc((size_t)S_ * DK_ * 2);
  u16* vp   = (u16*)alloc((size_t)S_ * DK_ * 2);
  u16* vpp  = (u16*)alloc((size_t)S_ * DK_ * 2);
  u16* vppT = (u16*)alloc((size_t)S_ * DK_ * 2);
  float* colsum = (float*)alloc((size_t)S_ * 4);
  float* part   = (float*)alloc((size_t)128 * DK_ * 4);
  u16* P    = (u16*)alloc((size_t)2080 * 128 * 128 * 2);
  if (ws_size < off) return;  // insufficient workspace -> visible as validation failure

  const int NQ = S_ * DM_ / 4, NW = DK_ * DM_ / 4;
  int cvt_blocks = (3 * NQ + 3 * NW + S_) / 256;
  sha_cvt_all<<<dim3(cvt_blocks), 256, 0, stream>>>(q, k, v, WQw, WKw, WVw,
                                                    qbf, kbf, vbf, wqb, wkb, wvb, colsum);
  sha_proj<<<dim3(4, 64, 3), 256, 0, stream>>>(qbf, kbf, vbf, wqb, wkb, wvb,
                                               WQb, WKb, WVb, qp, kp, vp);
  sha_pexp<<<dim3(2080), 256, 0, stream>>>(qp, kp, P, colsum);
  sha_scaleT<<<dim3(4, 64), 256, 0, stream>>>(vp, colsum, vpp, vppT, part);
  sha_sumb<<<dim3(4, 128), 128, 0, stream>>>(vpp, part, out);
  sha_pv<<<dim3(4, 64, 8), 256, 0, stream>>>(P, vppT, out);
}